// Round 4
// baseline (802.457 us; speedup 1.0000x reference)
//
#include <hip/hip_runtime.h>

#define NN      100000
#define MHE     200000
#define EE      2000000
#define H1      400000      // hedge keys (2 types)
#define K2N     200000      // node keys (2 types)
#define SCN     600000      // total CSR keys
#define SCB     586         // ceil(SCN/1024)

typedef unsigned short u16;
typedef unsigned int   u32;
typedef unsigned long long ull;
typedef __attribute__((ext_vector_type(8))) short  s16x8;
typedef __attribute__((ext_vector_type(2))) short  s16x2;
typedef __attribute__((ext_vector_type(4))) float  f32x4;
typedef __attribute__((ext_vector_type(4))) unsigned int u32x4;

__device__ __forceinline__ float bf2f(u16 u) { return __uint_as_float(((u32)u) << 16); }
__device__ __forceinline__ u16 f2bf(float f) {
    u32 u = __float_as_uint(f);
    return (u16)((u + 0x7fffu + ((u >> 16) & 1u)) >> 16);
}
__device__ __forceinline__ float ldv(const void* p, long i, int isf32) {
    return isf32 ? ((const float*)p)[i] : bf2f(((const u16*)p)[i]);
}
__device__ __forceinline__ u16 ldb(const void* p, long i, int isf32) {
    return isf32 ? f2bf(((const float*)p)[i]) : ((const u16*)p)[i];
}
__device__ __forceinline__ void stv(void* p, long i, float v, int isf32) {
    if (isf32) ((float*)p)[i] = v;
    else       ((u16*)p)[i] = f2bf(v);
}

union FragU { s16x8 v; ull q[2]; u16 u[8]; };

__device__ __forceinline__ s16x8 ld8bf(const void* p, long off, int isf32) {
    FragU f;
    if (isf32) {
        const float* fp = (const float*)p + off;
        f32x4 a = *(const f32x4*)fp;
        f32x4 b = *(const f32x4*)(fp + 4);
        f.u[0]=f2bf(a[0]); f.u[1]=f2bf(a[1]); f.u[2]=f2bf(a[2]); f.u[3]=f2bf(a[3]);
        f.u[4]=f2bf(b[0]); f.u[5]=f2bf(b[1]); f.u[6]=f2bf(b[2]); f.u[7]=f2bf(b[3]);
    } else {
        u32x4 w = *(const u32x4*)((const u16*)p + off);
        f.q[0] = ((ull)w[1] << 32) | w[0];
        f.q[1] = ((ull)w[3] << 32) | w[2];
    }
    return f.v;
}

__device__ __forceinline__ float sigm(float x) { return 1.f / (1.f + __expf(-x)); }

// ---- ws layout (4-byte units) ----
// proven ws budget: >= 8,016,000 floats (round-1 passed). high-water here: 7,813,963.
// BUGFIX vs round 3: Wcb is 2048 u16 = 1024 FLOATS (32x64 entries). Rounds 2/3
// reserved only 512 floats, so scanA's tot[] writes landed INSIDE Wcb ->
// garbage epilogue weights. flag/tot now placed past Wcb's true extent.
// lifetimes: bkt1 dies after hop1 -> aggb (hop2 output) aliases it.
//            off is histogram -> scanned in place -> atomic cursors in placeCSR
//            (post-place, off[k] = segment END; begin = off[k-1]).
#define OFF_BKT1  0            // u32[2,000,000]; aggb u32[1,600,000] aliases
#define OFF_BKT2  2000000      // u32[2,000,000]
#define OFF_EXB   4000000      // u32[3,200,000] -> ends 7,200,000
#define OFF_OFF   7200000      // int[600,000]   -> ends 7,800,000
#define OFF_BCOMB 7800000      // f32[64]
#define OFF_WIHB  7800064      // u16[12288] (6144 f)
#define OFF_WHHB  7806208      // u16[12288]
#define OFF_WCB   7812352      // u16[2048] (1024 f) -> ends 7,813,376
#define OFF_FLAG  7813376      // u32
#define OFF_TOT2  7813377      // int[SCB=586] -> ends 7,813,963

__global__ void detect_kernel(const u32* __restrict__ xw, u32* __restrict__ flag) {
    __shared__ int cnt;
    if (threadIdx.x == 0) cnt = 0;
    __syncthreads();
    int hits = 0;
    for (int i = threadIdx.x; i < 1024; i += 256) {
        float v = bf2f((u16)(xw[i] & 0xffffu));
        if (!(fabsf(v) < 1e10f)) hits++;
    }
    atomicAdd(&cnt, hits);
    __syncthreads();
    if (threadIdx.x == 0) flag[0] = (cnt >= 16) ? 1u : 0u;
}

#define XBASE 26688
__global__ __launch_bounds__(256) void setup_kernel(
        const void* __restrict__ W_conv, const void* __restrict__ b_conv,
        const void* __restrict__ W_mix,  const void* __restrict__ b_mix,
        const void* __restrict__ W_ih,   const void* __restrict__ W_hh,
        float* __restrict__ bcomb, u16* __restrict__ Wihb, u16* __restrict__ Whhb,
        u16* __restrict__ Wcb, const u32* __restrict__ flag) {
    int isf = (int)flag[0];
    int gid = blockIdx.x * 256 + threadIdx.x;
    if (gid < 12288) {
        Wihb[gid] = ldb(W_ih, gid, isf);
    } else if (gid < 24576) {
        int i = gid - 12288;
        Whhb[i] = ldb(W_hh, i, isf);
    } else if (gid < 26624) {
        int i = gid - 24576;
        int j = i >> 5, k = i & 31;
        int t0 = k >> 4, kk = k & 15;
        float acc = 0.f;
        for (int c = 0; c < 64; c++)
            acc += ldv(W_conv, (t0 * 16 + kk) * 64 + c, isf) * ldv(W_mix, (t0 * 64 + c) * 64 + j, isf);
        Wcb[i] = f2bf(acc);
    } else if (gid < XBASE) {
        int j = gid - 26624;
        if (j < 64) {
            float acc = ldv(b_mix, j, isf);
            for (int c = 0; c < 128; c++)
                acc += ldv(b_conv, c, isf) * ldv(W_mix, c * 64 + j, isf);
            bcomb[j] = acc;
        }
    }
}

// per-key histogram via L2 atomics: keys [0,H1) = hedge-keys, [H1,SCN) = node-keys
__global__ __launch_bounds__(256) void histoK(const int* __restrict__ en, const int* __restrict__ eh,
                                              const int* __restrict__ ea, int* __restrict__ cnt) {
    int i = blockIdx.x * 256 + threadIdx.x;
    int stride = gridDim.x * 256;
    for (; i < EE; i += stride) {
        int t = ea[i];
        atomicAdd(&cnt[t * MHE + eh[i]], 1);
        atomicAdd(&cnt[H1 + t * NN + en[i]], 1);
    }
}

// hierarchical exclusive scan of cnt[SCN] in place
__global__ __launch_bounds__(256) void scanA(int* __restrict__ a, int* __restrict__ tot) {
    __shared__ int lds[256];
    int g = blockIdx.x, t = threadIdx.x;
    int base = g * 1024 + t * 4;
    int v[4]; int s = 0;
    #pragma unroll
    for (int j = 0; j < 4; j++) { v[j] = (base + j < SCN) ? a[base + j] : 0; s += v[j]; }
    lds[t] = s;
    __syncthreads();
    for (int d = 1; d < 256; d <<= 1) {
        int tmp = (t >= d) ? lds[t - d] : 0;
        __syncthreads();
        lds[t] += tmp;
        __syncthreads();
    }
    int run = lds[t] - s;
    #pragma unroll
    for (int j = 0; j < 4; j++) { if (base + j < SCN) a[base + j] = run; run += v[j]; }
    if (t == 255) tot[g] = lds[255];
}

__global__ __launch_bounds__(1024) void scanB(int* __restrict__ tot) {
    __shared__ int lds[1024];
    int t = threadIdx.x;
    int v = (t < SCB) ? tot[t] : 0;
    lds[t] = v;
    __syncthreads();
    for (int d = 1; d < 1024; d <<= 1) {
        int tmp = (t >= d) ? lds[t - d] : 0;
        __syncthreads();
        lds[t] += tmp;
        __syncthreads();
    }
    if (t < SCB) tot[t] = lds[t] - v;
}

__global__ __launch_bounds__(256) void scanC(int* __restrict__ a, const int* __restrict__ tot) {
    int g = blockIdx.x, t = threadIdx.x;
    int add = tot[g];
    int base = g * 1024 + t * 4;
    #pragma unroll
    for (int j = 0; j < 4; j++)
        if (base + j < SCN) a[base + j] += add;
}

// CSR placement using off[] itself as atomic cursors.
// After this kernel, off[k] = END of segment k (begin = off[k-1], 0 for k=0).
__global__ __launch_bounds__(256) void placeCSR(const int* __restrict__ en, const int* __restrict__ eh,
                                                const int* __restrict__ ea, int* __restrict__ off,
                                                u32* __restrict__ bkt1, u32* __restrict__ bkt2) {
    int i = blockIdx.x * 256 + threadIdx.x;
    int stride = gridDim.x * 256;
    for (; i < EE; i += stride) {
        int t = ea[i], n = en[i];
        int k1 = t * MHE + eh[i];
        int p1 = atomicAdd(&off[k1], 1);
        bkt1[p1] = (u32)n;
        int p2 = atomicAdd(&off[H1 + t * NN + n], 1);
        bkt2[p2 - EE] = (u32)k1;
    }
}

// hop1: one 8-lane group per hedge-key; register accumulation, Binv = 1/deg free.
// Reads x directly (bf16: packed u32 pairs; f32: scalar pair). NO LDS/atomics/barriers.
__global__ __launch_bounds__(256) void hop1(const int* __restrict__ off, const u32* __restrict__ bkt1,
                                            const void* __restrict__ x, u32* __restrict__ exb,
                                            const u32* __restrict__ flag) {
    int isf = (int)flag[0];
    int tid = threadIdx.x;
    int sub = tid & 7, grp = tid >> 3;
    int h = blockIdx.x * 32 + grp;
    if (h >= H1) return;
    int beg = h ? off[h - 1] : 0, end = off[h];
    float a0 = 0.f, a1 = 0.f;
    if (isf) {
        const float* xf = (const float*)x;
        for (int j = beg; j < end; j++) {
            long n0 = (long)bkt1[j];
            a0 += xf[n0 * 16 + 2 * sub];
            a1 += xf[n0 * 16 + 2 * sub + 1];
        }
    } else {
        const u32* xu = (const u32*)x;
        int j = beg;
        for (; j + 1 < end; j += 2) {
            u32 n0 = bkt1[j], n1 = bkt1[j + 1];
            u32 w0 = xu[(long)n0 * 8 + sub];
            u32 w1 = xu[(long)n1 * 8 + sub];
            a0 += bf2f((u16)(w0 & 0xffffu)) + bf2f((u16)(w1 & 0xffffu));
            a1 += bf2f((u16)(w0 >> 16))     + bf2f((u16)(w1 >> 16));
        }
        if (j < end) {
            u32 w0 = xu[(long)bkt1[j] * 8 + sub];
            a0 += bf2f((u16)(w0 & 0xffffu));
            a1 += bf2f((u16)(w0 >> 16));
        }
    }
    int d = end - beg;
    float inv = d > 0 ? 1.0f / (float)d : 0.f;
    exb[(long)h * 8 + sub] = (u32)f2bf(a0 * inv) | ((u32)f2bf(a1 * inv) << 16);
}

// hop2: one 8-lane group per node-key; gathers exb rows, Dinv folded, writes aggb
// (zeros for deg-0 keys -> no memset of aggb needed).
__global__ __launch_bounds__(256) void hop2(const int* __restrict__ off, const u32* __restrict__ bkt2,
                                            const u32* __restrict__ exb, u32* __restrict__ aggb) {
    int tid = threadIdx.x;
    int sub = tid & 7, grp = tid >> 3;
    int k = blockIdx.x * 32 + grp;
    if (k >= K2N) return;
    int beg = off[H1 + k - 1] - EE;   // k=0: off[H1-1] = EE -> beg 0
    int end = off[H1 + k] - EE;
    float a0 = 0.f, a1 = 0.f;
    int j = beg;
    for (; j + 1 < end; j += 2) {
        u32 k0 = bkt2[j], k1 = bkt2[j + 1];
        u32 w0 = exb[(long)k0 * 8 + sub];
        u32 w1 = exb[(long)k1 * 8 + sub];
        a0 += bf2f((u16)(w0 & 0xffffu)) + bf2f((u16)(w1 & 0xffffu));
        a1 += bf2f((u16)(w0 >> 16))     + bf2f((u16)(w1 >> 16));
    }
    if (j < end) {
        u32 k0 = bkt2[j];
        u32 w0 = exb[(long)k0 * 8 + sub];
        a0 += bf2f((u16)(w0 & 0xffffu));
        a1 += bf2f((u16)(w0 >> 16));
    }
    int d = end - beg;
    float inv = d > 0 ? 1.0f / (float)d : 0.f;
    aggb[(long)k * 8 + sub] = (u32)f2bf(a0 * inv) | ((u32)f2bf(a1 * inv) << 16);
}

// MFMA epilogue; stage-1 A loads aggb rows directly (Dinv pre-folded in hop2)
__global__ __launch_bounds__(256) void epilogue(const u32* __restrict__ aggb,
                                                const float* __restrict__ bcomb,
                                                const u16* __restrict__ Wihb,
                                                const u16* __restrict__ Whhb,
                                                const u16* __restrict__ Wcb,
                                                const void* __restrict__ b_ih, const void* __restrict__ b_hh,
                                                const void* __restrict__ h_prev,
                                                const void* __restrict__ W_out, const void* __restrict__ b_out,
                                                void* __restrict__ out,
                                                const u32* __restrict__ flag) {
    __shared__ u16 hA[4][16][72];
    int isf = (int)flag[0];
    int tid = threadIdx.x;
    int w = tid >> 6, lane = tid & 63;
    int cl = lane & 15, q = lane >> 4;
    u16* hAw = &hA[w][0][0];

    float bcj[4], br[4], bz[4], bin_[4], bhn[4], wo0[4], wo1[4], wo2[4];
    #pragma unroll
    for (int c = 0; c < 4; c++) {
        int j = c * 16 + cl;
        bcj[c]  = bcomb[j];
        br[c]   = ldv(b_ih, j, isf)       + ldv(b_hh, j, isf);
        bz[c]   = ldv(b_ih, 64 + j, isf)  + ldv(b_hh, 64 + j, isf);
        bin_[c] = ldv(b_ih, 128 + j, isf);
        bhn[c]  = ldv(b_hh, 128 + j, isf);
        wo0[c]  = ldv(W_out, (long)j * 64 + 0, isf);
        wo1[c]  = ldv(W_out, (long)j * 64 + 1, isf);
        wo2[c]  = ldv(W_out, (long)j * 64 + 2, isf);
    }
    float bo0 = ldv(b_out, 0, isf), bo1 = ldv(b_out, 1, isf), bo2 = ldv(b_out, 2, isf);

    for (int wt = blockIdx.x * 4 + w; wt < NN / 16; wt += gridDim.x * 4) {
        long nb = (long)wt * 16;
        {
            int m = cl;
            int t0 = q >> 1;
            long nidx = nb + m;
            const u32* ap = aggb + ((long)t0 * NN + nidx) * 8 + (q & 1) * 4;
            u32x4 aw = *(const u32x4*)ap;
            FragU fa;
            fa.q[0] = ((ull)aw[1] << 32) | aw[0];
            fa.q[1] = ((ull)aw[3] << 32) | aw[2];
            f32x4 hacc[4];
            #pragma unroll
            for (int c = 0; c < 4; c++) {
                hacc[c] = (f32x4){0.f, 0.f, 0.f, 0.f};
                s16x8 bfr = *(const s16x8*)(Wcb + (c * 16 + cl) * 32 + q * 8);
                hacc[c] = __builtin_amdgcn_mfma_f32_16x16x32_bf16(fa.v, bfr, hacc[c], 0, 0, 0);
            }
            #pragma unroll
            for (int c = 0; c < 4; c++) {
                #pragma unroll
                for (int reg = 0; reg < 4; reg++) {
                    int row = q * 4 + reg;
                    float hv = fmaxf(hacc[c][reg] + bcj[c], 0.f);
                    hAw[row * 72 + c * 16 + cl] = f2bf(hv);
                }
            }
        }
        asm volatile("" ::: "memory");
        int m = cl;
        const u16* hrow = hAw + m * 72;
        FragU ha0, ha1;
        #pragma unroll
        for (int j = 0; j < 8; j++) {
            ha0.u[j] = hrow[q * 8 + j];
            ha1.u[j] = hrow[32 + q * 8 + j];
        }
        s16x8 hp0 = ld8bf(h_prev, (nb + m) * 64 + q * 8, isf);
        s16x8 hp1 = ld8bf(h_prev, (nb + m) * 64 + 32 + q * 8, isf);

        f32x4 accr[4], accz[4], accin[4], acchn[4];
        #pragma unroll
        for (int c = 0; c < 4; c++) {
            accr[c]  = (f32x4){br[c], br[c], br[c], br[c]};
            accz[c]  = (f32x4){bz[c], bz[c], bz[c], bz[c]};
            accin[c] = (f32x4){bin_[c], bin_[c], bin_[c], bin_[c]};
            acchn[c] = (f32x4){bhn[c], bhn[c], bhn[c], bhn[c]};
        }
        #pragma unroll
        for (int s = 0; s < 2; s++) {
            s16x8 hf  = s ? ha1.v : ha0.v;
            s16x8 hpf = s ? hp1 : hp0;
            int ko = s * 32 + q * 8;
            #pragma unroll
            for (int c = 0; c < 4; c++) {
                int rr = c * 16 + cl;
                s16x8 bir  = *(const s16x8*)(Wihb + (long)rr * 64 + ko);
                s16x8 bhr  = *(const s16x8*)(Whhb + (long)rr * 64 + ko);
                s16x8 biz  = *(const s16x8*)(Wihb + (long)(64 + rr) * 64 + ko);
                s16x8 bhz  = *(const s16x8*)(Whhb + (long)(64 + rr) * 64 + ko);
                s16x8 bin2 = *(const s16x8*)(Wihb + (long)(128 + rr) * 64 + ko);
                s16x8 bhn2 = *(const s16x8*)(Whhb + (long)(128 + rr) * 64 + ko);
                accr[c]  = __builtin_amdgcn_mfma_f32_16x16x32_bf16(hf,  bir, accr[c], 0, 0, 0);
                accr[c]  = __builtin_amdgcn_mfma_f32_16x16x32_bf16(hpf, bhr, accr[c], 0, 0, 0);
                accz[c]  = __builtin_amdgcn_mfma_f32_16x16x32_bf16(hf,  biz, accz[c], 0, 0, 0);
                accz[c]  = __builtin_amdgcn_mfma_f32_16x16x32_bf16(hpf, bhz, accz[c], 0, 0, 0);
                accin[c] = __builtin_amdgcn_mfma_f32_16x16x32_bf16(hf,  bin2, accin[c], 0, 0, 0);
                acchn[c] = __builtin_amdgcn_mfma_f32_16x16x32_bf16(hpf, bhn2, acchn[c], 0, 0, 0);
            }
        }
        float p0[4] = {0,0,0,0}, p1[4] = {0,0,0,0}, p2[4] = {0,0,0,0};
        #pragma unroll
        for (int c = 0; c < 4; c++) {
            #pragma unroll
            for (int reg = 0; reg < 4; reg++) {
                float rr = sigm(accr[c][reg]);
                float zz = sigm(accz[c][reg]);
                float ng = tanhf(accin[c][reg] + rr * acchn[c][reg]);
                long n = nb + q * 4 + reg;
                long j = c * 16 + cl;
                float hp = ldv(h_prev, n * 64 + j, isf);
                float hx = (1.f - zz) * ng + zz * hp;
                stv(out, n * 64 + j, hx, isf);
                p0[reg] += hx * wo0[c];
                p1[reg] += hx * wo1[c];
                p2[reg] += hx * wo2[c];
            }
        }
        #pragma unroll
        for (int reg = 0; reg < 4; reg++) {
            #pragma unroll
            for (int off2 = 1; off2 < 16; off2 <<= 1) {
                p0[reg] += __shfl_xor(p0[reg], off2);
                p1[reg] += __shfl_xor(p1[reg], off2);
                p2[reg] += __shfl_xor(p2[reg], off2);
            }
        }
        if (cl == 0) {
            #pragma unroll
            for (int reg = 0; reg < 4; reg++) {
                long n = nb + q * 4 + reg;
                long pb = (long)NN * 64 + n * 3;
                stv(out, pb + 0, p0[reg] + bo0, isf);
                stv(out, pb + 1, p1[reg] + bo1, isf);
                stv(out, pb + 2, p2[reg] + bo2, isf);
            }
        }
    }
}

extern "C" void kernel_launch(void* const* d_in, const int* in_sizes, int n_in,
                              void* d_out, int out_size, void* d_ws, size_t ws_size,
                              hipStream_t stream) {
    const void* x      = d_in[0];
    const void* h_prev = d_in[1];
    const int* en      = (const int*)d_in[2];
    const int* eh      = (const int*)d_in[3];
    const int* ea      = (const int*)d_in[4];
    const void* W_conv = d_in[5];
    const void* b_conv = d_in[6];
    const void* W_mix  = d_in[7];
    const void* b_mix  = d_in[8];
    const void* W_ih   = d_in[9];
    const void* W_hh   = d_in[10];
    const void* b_ih   = d_in[11];
    const void* b_hh   = d_in[12];
    const void* W_out  = d_in[13];
    const void* b_out  = d_in[14];
    void* out          = d_out;

    float* ws    = (float*)d_ws;
    u32* bkt1    = (u32*)(ws + OFF_BKT1);
    u32* bkt2    = (u32*)(ws + OFF_BKT2);
    u32* exb     = (u32*)(ws + OFF_EXB);
    int* off     = (int*)(ws + OFF_OFF);
    u32* aggb    = (u32*)(ws + OFF_BKT1);   // alias: bkt1 dead after hop1
    float* bcomb = ws + OFF_BCOMB;
    u16* Wihb    = (u16*)(ws + OFF_WIHB);
    u16* Whhb    = (u16*)(ws + OFF_WHHB);
    u16* Wcb     = (u16*)(ws + OFF_WCB);
    u32* flag    = (u32*)(ws + OFF_FLAG);
    int* tot     = (int*)(ws + OFF_TOT2);

    detect_kernel<<<1, 256, 0, stream>>>((const u32*)x, flag);
    setup_kernel<<<(XBASE + 255) / 256, 256, 0, stream>>>(
        W_conv, b_conv, W_mix, b_mix, W_ih, W_hh,
        bcomb, Wihb, Whhb, Wcb, flag);
    (void)hipMemsetAsync(off, 0, (size_t)SCN * 4, stream);
    histoK<<<2048, 256, 0, stream>>>(en, eh, ea, off);
    scanA<<<SCB, 256, 0, stream>>>(off, tot);
    scanB<<<1, 1024, 0, stream>>>(tot);
    scanC<<<SCB, 256, 0, stream>>>(off, tot);
    placeCSR<<<2048, 256, 0, stream>>>(en, eh, ea, off, bkt1, bkt2);
    hop1<<<(H1 + 31) / 32, 256, 0, stream>>>(off, bkt1, x, exb, flag);
    hop2<<<(K2N + 31) / 32, 256, 0, stream>>>(off, bkt2, exb, aggb);
    epilogue<<<1563, 256, 0, stream>>>(aggb, bcomb, Wihb, Whhb, Wcb,
                                       b_ih, b_hh, h_prev, W_out, b_out, out, flag);
}

// Round 6
// 390.839 us; speedup vs baseline: 2.0532x; 2.0532x over previous
//
#include <hip/hip_runtime.h>

#define NN      100000
#define MHE     200000
#define EE      2000000
#define H1      400000      // hedge keys (2 types)
#define K2N     200000      // node keys (2 types)
#define NB1     782         // side-1 coarse buckets (512 hedge-keys each)
#define NB2     391         // side-2 coarse buckets (512 node-keys each)
#define NCB2    160         // partition blocks
#define CHK2    12500       // edges per partition block (160*12500 = EE exactly)
#define FCN     187680      // (NB1+NB2)*NCB2 flat counters
#define SCB2    184         // ceil(FCN/1024)
#define CAP1    3584        // max items per side-1 bucket (mean 2560, +20 sigma)
#define CAP2    6144        // max items per side-2 bucket (mean 5120, +14 sigma)

typedef unsigned short u16;
typedef unsigned int   u32;
typedef unsigned long long ull;
typedef __attribute__((ext_vector_type(8))) short  s16x8;
typedef __attribute__((ext_vector_type(4))) float  f32x4;
typedef __attribute__((ext_vector_type(4))) unsigned int u32x4;

__device__ __forceinline__ float bf2f(u16 u) { return __uint_as_float(((u32)u) << 16); }
__device__ __forceinline__ u16 f2bf(float f) {
    u32 u = __float_as_uint(f);
    return (u16)((u + 0x7fffu + ((u >> 16) & 1u)) >> 16);
}
__device__ __forceinline__ float ldv(const void* p, long i, int isf32) {
    return isf32 ? ((const float*)p)[i] : bf2f(((const u16*)p)[i]);
}
__device__ __forceinline__ u16 ldb(const void* p, long i, int isf32) {
    return isf32 ? f2bf(((const float*)p)[i]) : ((const u16*)p)[i];
}
__device__ __forceinline__ void stv(void* p, long i, float v, int isf32) {
    if (isf32) ((float*)p)[i] = v;
    else       ((u16*)p)[i] = f2bf(v);
}

union FragU { s16x8 v; ull q[2]; u16 u[8]; };

__device__ __forceinline__ s16x8 ld8bf(const void* p, long off, int isf32) {
    FragU f;
    if (isf32) {
        const float* fp = (const float*)p + off;
        f32x4 a = *(const f32x4*)fp;
        f32x4 b = *(const f32x4*)(fp + 4);
        f.u[0]=f2bf(a[0]); f.u[1]=f2bf(a[1]); f.u[2]=f2bf(a[2]); f.u[3]=f2bf(a[3]);
        f.u[4]=f2bf(b[0]); f.u[5]=f2bf(b[1]); f.u[6]=f2bf(b[2]); f.u[7]=f2bf(b[3]);
    } else {
        u32x4 w = *(const u32x4*)((const u16*)p + off);
        f.q[0] = ((ull)w[1] << 32) | w[0];
        f.q[1] = ((ull)w[3] << 32) | w[2];
    }
    return f.v;
}

__device__ __forceinline__ float sigm(float x) { return 1.f / (1.f + __expf(-x)); }

// ---- ws layout (4-byte units) ----
// proven ws budget: >= 8,016,000 floats. high-water here: 7,401,242.
// lifetimes: bkt1 dies after hopA -> aggb (hopB output) aliases it.
#define OFF_BKT1  0            // u32[2,000,000]; aggb u32[1,600,000] aliases
#define OFF_BKT2  2000000      // u32[2,000,000]
#define OFF_EXB   4000000      // u32[3,200,000] -> ends 7,200,000
#define OFF_FSC   7200000      // int[FCN+1]     -> ends 7,387,681 (scan + sentinel)
#define OFF_TOT   7387681      // int[SCB2=184]  -> ends 7,387,865
#define OFF_BCOMB 7387865      // f32[64]
#define OFF_WIHB  7387929      // u16[12288] (6144 f)
#define OFF_WHHB  7394073      // u16[12288]
#define OFF_WCB   7400217      // u16[2048] (1024 f)
#define OFF_FLAG  7401241      // u32 -> ends 7,401,242

__global__ void detect_kernel(const u32* __restrict__ xw, u32* __restrict__ flag) {
    __shared__ int cnt;
    if (threadIdx.x == 0) cnt = 0;
    __syncthreads();
    int hits = 0;
    for (int i = threadIdx.x; i < 1024; i += 256) {
        float v = bf2f((u16)(xw[i] & 0xffffu));
        if (!(fabsf(v) < 1e10f)) hits++;
    }
    atomicAdd(&cnt, hits);
    __syncthreads();
    if (threadIdx.x == 0) flag[0] = (cnt >= 16) ? 1u : 0u;
}

#define XBASE 26688
__global__ __launch_bounds__(256) void setup_kernel(
        const void* __restrict__ W_conv, const void* __restrict__ b_conv,
        const void* __restrict__ W_mix,  const void* __restrict__ b_mix,
        const void* __restrict__ W_ih,   const void* __restrict__ W_hh,
        float* __restrict__ bcomb, u16* __restrict__ Wihb, u16* __restrict__ Whhb,
        u16* __restrict__ Wcb, const u32* __restrict__ flag) {
    int isf = (int)flag[0];
    int gid = blockIdx.x * 256 + threadIdx.x;
    if (gid < 12288) {
        Wihb[gid] = ldb(W_ih, gid, isf);
    } else if (gid < 24576) {
        int i = gid - 12288;
        Whhb[i] = ldb(W_hh, i, isf);
    } else if (gid < 26624) {
        int i = gid - 24576;
        int j = i >> 5, k = i & 31;
        int t0 = k >> 4, kk = k & 15;
        float acc = 0.f;
        for (int c = 0; c < 64; c++)
            acc += ldv(W_conv, (t0 * 16 + kk) * 64 + c, isf) * ldv(W_mix, (t0 * 64 + c) * 64 + j, isf);
        Wcb[i] = f2bf(acc);
    } else if (gid < XBASE) {
        int j = gid - 26624;
        if (j < 64) {
            float acc = ldv(b_mix, j, isf);
            for (int c = 0; c < 128; c++)
                acc += ldv(b_conv, c, isf) * ldv(W_mix, c * 64 + j, isf);
            bcomb[j] = acc;
        }
    }
}

// per-block coarse histograms, both sides fused. fcnt layout: [bucket][block]
// (side-1 buckets 0..NB1-1, then side-2 buckets). LDS int atomics only.
__global__ __launch_bounds__(1024) void countC(const int* __restrict__ en, const int* __restrict__ eh,
                                               const int* __restrict__ ea, int* __restrict__ fcnt) {
    __shared__ int c[NB1 + NB2];
    int g = blockIdx.x, tid = threadIdx.x;
    for (int i = tid; i < NB1 + NB2; i += 1024) c[i] = 0;
    __syncthreads();
    int s = g * CHK2;
    for (int i = s + tid; i < s + CHK2; i += 1024) {
        int t = ea[i];
        atomicAdd(&c[(t * MHE + eh[i]) >> 9], 1);
        atomicAdd(&c[NB1 + ((t * NN + en[i]) >> 9)], 1);
    }
    __syncthreads();
    for (int b = tid; b < NB1 + NB2; b += 1024) fcnt[b * NCB2 + g] = c[b];
}

// hierarchical exclusive scan of fcnt[FCN] in place
__global__ __launch_bounds__(256) void scanA2(int* __restrict__ a, int* __restrict__ tot) {
    __shared__ int lds[256];
    int g = blockIdx.x, t = threadIdx.x;
    int base = g * 1024 + t * 4;
    int v[4]; int s = 0;
    #pragma unroll
    for (int j = 0; j < 4; j++) { v[j] = (base + j < FCN) ? a[base + j] : 0; s += v[j]; }
    lds[t] = s;
    __syncthreads();
    for (int d = 1; d < 256; d <<= 1) {
        int tmp = (t >= d) ? lds[t - d] : 0;
        __syncthreads();
        lds[t] += tmp;
        __syncthreads();
    }
    int run = lds[t] - s;
    #pragma unroll
    for (int j = 0; j < 4; j++) { if (base + j < FCN) a[base + j] = run; run += v[j]; }
    if (t == 255) tot[g] = lds[255];
}

__global__ __launch_bounds__(1024) void scanB2(int* __restrict__ tot) {
    __shared__ int lds[1024];
    int t = threadIdx.x;
    int v = (t < SCB2) ? tot[t] : 0;
    lds[t] = v;
    __syncthreads();
    for (int d = 1; d < 1024; d <<= 1) {
        int tmp = (t >= d) ? lds[t - d] : 0;
        __syncthreads();
        lds[t] += tmp;
        __syncthreads();
    }
    if (t < SCB2) tot[t] = lds[t] - v;
}

__global__ __launch_bounds__(256) void scanC2(int* __restrict__ a, const int* __restrict__ tot) {
    int g = blockIdx.x, t = threadIdx.x;
    int add = tot[g];
    int base = g * 1024 + t * 4;
    #pragma unroll
    for (int j = 0; j < 4; j++)
        if (base + j < FCN) a[base + j] += add;
    if (g == 0 && t == 0) a[FCN] = 2 * EE;   // sentinel: end of side-2
}

// partition pass: block-local counting sort into LDS, then bucket-run copies to
// global (runs ~16 items -> ~full 64B lines; NO global atomics, NO 4B scatter).
template<int SIDE>
__global__ __launch_bounds__(1024) void placeC(const int* __restrict__ en, const int* __restrict__ eh,
                                               const int* __restrict__ ea, const int* __restrict__ fscan,
                                               u32* __restrict__ bktout) {
    __shared__ u32 sarr[CHK2];       // 50 KB
    __shared__ int sbuf[1024];
    __shared__ int cnt[NB1];
    __shared__ int loff[NB1];
    const int nb = SIDE ? NB2 : NB1;
    const int fbase = SIDE ? NB1 * NCB2 : 0;
    int g = blockIdx.x, tid = threadIdx.x;
    for (int i = tid; i < nb; i += 1024) cnt[i] = 0;
    __syncthreads();
    int s = g * CHK2;
    // pass A: coarse count
    for (int i = s + tid; i < s + CHK2; i += 1024) {
        int t = ea[i];
        int k = SIDE ? (t * NN + en[i]) : (t * MHE + eh[i]);
        atomicAdd(&cnt[k >> 9], 1);
    }
    __syncthreads();
    // LDS exclusive scan of cnt[nb] -> loff
    int v = (tid < nb) ? cnt[tid] : 0;
    sbuf[tid] = v;
    __syncthreads();
    for (int d = 1; d < 1024; d <<= 1) {
        int tmp = (tid >= d) ? sbuf[tid - d] : 0;
        __syncthreads();
        sbuf[tid] += tmp;
        __syncthreads();
    }
    if (tid < nb) { loff[tid] = sbuf[tid] - v; cnt[tid] = 0; }
    __syncthreads();
    // pass B: rank + stage into bucket-sorted LDS
    for (int i = s + tid; i < s + CHK2; i += 1024) {
        int t = ea[i]; int nd = en[i]; int hh = eh[i];
        int k = SIDE ? (t * NN + nd) : (t * MHE + hh);
        int b = k >> 9;
        int r = atomicAdd(&cnt[b], 1);
        u32 pay = SIDE ? (((u32)(k & 511) << 19) | (u32)(t * MHE + hh))
                       : (((u32)(k & 511) << 17) | (u32)nd);
        sarr[loff[b] + r] = pay;
    }
    __syncthreads();
    // copy: slot -> bucket via binary search; bucket-runs are contiguous in global
    for (int s2 = tid; s2 < CHK2; s2 += 1024) {
        int lo = 0, hi = nb - 1;
        while (lo < hi) {
            int mid = (lo + hi + 1) >> 1;
            if (loff[mid] <= s2) lo = mid; else hi = mid - 1;
        }
        int gp = fscan[fbase + lo * NCB2 + g] + (s2 - loff[lo]);
        if (SIDE) gp -= EE;
        bktout[gp] = sarr[s2];
    }
}

// hopA: one block per side-1 coarse bucket. Build fine (512-key) CSR in LDS,
// then 8-lane groups aggregate x rows per hedge key in REGISTERS, fold Binv,
// write exb coalesced. No f32 atomics anywhere.
__global__ __launch_bounds__(512) void hopA(const int* __restrict__ fscan, const u32* __restrict__ bkt1,
                                            const void* __restrict__ x, u32* __restrict__ exb,
                                            const u32* __restrict__ flag) {
    __shared__ int fcnt[512], foff[513], sbuf[512];
    __shared__ int snod[CAP1];
    int isf = (int)flag[0];
    int c = blockIdx.x, tid = threadIdx.x;
    int beg = fscan[c * NCB2], end = fscan[(c + 1) * NCB2];
    fcnt[tid] = 0;
    __syncthreads();
    for (int i = beg + tid; i < end; i += 512)
        atomicAdd(&fcnt[bkt1[i] >> 17], 1);
    __syncthreads();
    int v = fcnt[tid];
    sbuf[tid] = v;
    __syncthreads();
    for (int d = 1; d < 512; d <<= 1) {
        int tmp = (tid >= d) ? sbuf[tid - d] : 0;
        __syncthreads();
        sbuf[tid] += tmp;
        __syncthreads();
    }
    foff[tid] = sbuf[tid] - v;
    fcnt[tid] = 0;
    if (tid == 511) foff[512] = sbuf[511];
    __syncthreads();
    for (int i = beg + tid; i < end; i += 512) {
        u32 p = bkt1[i];
        int k = (int)(p >> 17);
        int r = atomicAdd(&fcnt[k], 1);
        snod[foff[k] + r] = (int)(p & 0x1FFFFu);
    }
    __syncthreads();
    int sub = tid & 7, grp = tid >> 3;     // 64 groups of 8 lanes
    for (int kk = grp; kk < 512; kk += 64) {
        int key = c * 512 + kk;
        if (key >= H1) break;
        int fb = foff[kk], fe = foff[kk + 1];
        float a0 = 0.f, a1 = 0.f;
        if (isf) {
            const float* xf = (const float*)x;
            for (int j = fb; j < fe; j++) {
                long n0 = (long)snod[j];
                a0 += xf[n0 * 16 + 2 * sub];
                a1 += xf[n0 * 16 + 2 * sub + 1];
            }
        } else {
            const u32* xu = (const u32*)x;
            for (int j = fb; j < fe; j++) {
                u32 w = xu[(long)snod[j] * 8 + sub];
                a0 += bf2f((u16)(w & 0xffffu));
                a1 += bf2f((u16)(w >> 16));
            }
        }
        int d = fe - fb;
        float inv = d > 0 ? 1.0f / (float)d : 0.f;
        exb[(long)key * 8 + sub] = (u32)f2bf(a0 * inv) | ((u32)f2bf(a1 * inv) << 16);
    }
}

// hopB: one block per side-2 coarse bucket; gather exb rows per node key,
// fold Dinv, write aggb (zeros for deg-0 keys -> no memset needed).
__global__ __launch_bounds__(512) void hopB(const int* __restrict__ fscan, const u32* __restrict__ bkt2,
                                            const u32* __restrict__ exb, u32* __restrict__ aggb) {
    __shared__ int fcnt[512], foff[513], sbuf[512];
    __shared__ int shed[CAP2];
    int c = blockIdx.x, tid = threadIdx.x;
    int beg = fscan[NB1 * NCB2 + c * NCB2] - EE;
    int end = fscan[NB1 * NCB2 + (c + 1) * NCB2] - EE;
    fcnt[tid] = 0;
    __syncthreads();
    for (int i = beg + tid; i < end; i += 512)
        atomicAdd(&fcnt[bkt2[i] >> 19], 1);
    __syncthreads();
    int v = fcnt[tid];
    sbuf[tid] = v;
    __syncthreads();
    for (int d = 1; d < 512; d <<= 1) {
        int tmp = (tid >= d) ? sbuf[tid - d] : 0;
        __syncthreads();
        sbuf[tid] += tmp;
        __syncthreads();
    }
    foff[tid] = sbuf[tid] - v;
    fcnt[tid] = 0;
    if (tid == 511) foff[512] = sbuf[511];
    __syncthreads();
    for (int i = beg + tid; i < end; i += 512) {
        u32 p = bkt2[i];
        int k = (int)(p >> 19);
        int r = atomicAdd(&fcnt[k], 1);
        shed[foff[k] + r] = (int)(p & 0x7FFFFu);
    }
    __syncthreads();
    int sub = tid & 7, grp = tid >> 3;
    for (int kk = grp; kk < 512; kk += 64) {
        int key = c * 512 + kk;
        if (key >= K2N) break;
        int fb = foff[kk], fe = foff[kk + 1];
        float a0 = 0.f, a1 = 0.f;
        for (int j = fb; j < fe; j++) {
            u32 w = exb[(long)shed[j] * 8 + sub];
            a0 += bf2f((u16)(w & 0xffffu));
            a1 += bf2f((u16)(w >> 16));
        }
        int d = fe - fb;
        float inv = d > 0 ? 1.0f / (float)d : 0.f;
        aggb[(long)key * 8 + sub] = (u32)f2bf(a0 * inv) | ((u32)f2bf(a1 * inv) << 16);
    }
}

// MFMA epilogue; stage-1 A loads aggb rows directly (Dinv pre-folded in hopB)
__global__ __launch_bounds__(256) void epilogue(const u32* __restrict__ aggb,
                                                const float* __restrict__ bcomb,
                                                const u16* __restrict__ Wihb,
                                                const u16* __restrict__ Whhb,
                                                const u16* __restrict__ Wcb,
                                                const void* __restrict__ b_ih, const void* __restrict__ b_hh,
                                                const void* __restrict__ h_prev,
                                                const void* __restrict__ W_out, const void* __restrict__ b_out,
                                                void* __restrict__ out,
                                                const u32* __restrict__ flag) {
    __shared__ u16 hA[4][16][72];
    int isf = (int)flag[0];
    int tid = threadIdx.x;
    int w = tid >> 6, lane = tid & 63;
    int cl = lane & 15, q = lane >> 4;
    u16* hAw = &hA[w][0][0];

    float bcj[4], br[4], bz[4], bin_[4], bhn[4], wo0[4], wo1[4], wo2[4];
    #pragma unroll
    for (int c = 0; c < 4; c++) {
        int j = c * 16 + cl;
        bcj[c]  = bcomb[j];
        br[c]   = ldv(b_ih, j, isf)       + ldv(b_hh, j, isf);
        bz[c]   = ldv(b_ih, 64 + j, isf)  + ldv(b_hh, 64 + j, isf);
        bin_[c] = ldv(b_ih, 128 + j, isf);
        bhn[c]  = ldv(b_hh, 128 + j, isf);
        wo0[c]  = ldv(W_out, (long)j * 64 + 0, isf);
        wo1[c]  = ldv(W_out, (long)j * 64 + 1, isf);
        wo2[c]  = ldv(W_out, (long)j * 64 + 2, isf);
    }
    float bo0 = ldv(b_out, 0, isf), bo1 = ldv(b_out, 1, isf), bo2 = ldv(b_out, 2, isf);

    for (int wt = blockIdx.x * 4 + w; wt < NN / 16; wt += gridDim.x * 4) {
        long nb = (long)wt * 16;
        {
            int m = cl;
            int t0 = q >> 1;
            long nidx = nb + m;
            const u32* ap = aggb + ((long)t0 * NN + nidx) * 8 + (q & 1) * 4;
            u32x4 aw = *(const u32x4*)ap;
            FragU fa;
            fa.q[0] = ((ull)aw[1] << 32) | aw[0];
            fa.q[1] = ((ull)aw[3] << 32) | aw[2];
            f32x4 hacc[4];
            #pragma unroll
            for (int c = 0; c < 4; c++) {
                hacc[c] = (f32x4){0.f, 0.f, 0.f, 0.f};
                s16x8 bfr = *(const s16x8*)(Wcb + (c * 16 + cl) * 32 + q * 8);
                hacc[c] = __builtin_amdgcn_mfma_f32_16x16x32_bf16(fa.v, bfr, hacc[c], 0, 0, 0);
            }
            #pragma unroll
            for (int c = 0; c < 4; c++) {
                #pragma unroll
                for (int reg = 0; reg < 4; reg++) {
                    int row = q * 4 + reg;
                    float hv = fmaxf(hacc[c][reg] + bcj[c], 0.f);
                    hAw[row * 72 + c * 16 + cl] = f2bf(hv);
                }
            }
        }
        asm volatile("" ::: "memory");
        int m = cl;
        const u16* hrow = hAw + m * 72;
        FragU ha0, ha1;
        #pragma unroll
        for (int j = 0; j < 8; j++) {
            ha0.u[j] = hrow[q * 8 + j];
            ha1.u[j] = hrow[32 + q * 8 + j];
        }
        s16x8 hp0 = ld8bf(h_prev, (nb + m) * 64 + q * 8, isf);
        s16x8 hp1 = ld8bf(h_prev, (nb + m) * 64 + 32 + q * 8, isf);

        f32x4 accr[4], accz[4], accin[4], acchn[4];
        #pragma unroll
        for (int c = 0; c < 4; c++) {
            accr[c]  = (f32x4){br[c], br[c], br[c], br[c]};
            accz[c]  = (f32x4){bz[c], bz[c], bz[c], bz[c]};
            accin[c] = (f32x4){bin_[c], bin_[c], bin_[c], bin_[c]};
            acchn[c] = (f32x4){bhn[c], bhn[c], bhn[c], bhn[c]};
        }
        #pragma unroll
        for (int s = 0; s < 2; s++) {
            s16x8 hf  = s ? ha1.v : ha0.v;
            s16x8 hpf = s ? hp1 : hp0;
            int ko = s * 32 + q * 8;
            #pragma unroll
            for (int c = 0; c < 4; c++) {
                int rr = c * 16 + cl;
                s16x8 bir  = *(const s16x8*)(Wihb + (long)rr * 64 + ko);
                s16x8 bhr  = *(const s16x8*)(Whhb + (long)rr * 64 + ko);
                s16x8 biz  = *(const s16x8*)(Wihb + (long)(64 + rr) * 64 + ko);
                s16x8 bhz  = *(const s16x8*)(Whhb + (long)(64 + rr) * 64 + ko);
                s16x8 bin2 = *(const s16x8*)(Wihb + (long)(128 + rr) * 64 + ko);
                s16x8 bhn2 = *(const s16x8*)(Whhb + (long)(128 + rr) * 64 + ko);
                accr[c]  = __builtin_amdgcn_mfma_f32_16x16x32_bf16(hf,  bir, accr[c], 0, 0, 0);
                accr[c]  = __builtin_amdgcn_mfma_f32_16x16x32_bf16(hpf, bhr, accr[c], 0, 0, 0);
                accz[c]  = __builtin_amdgcn_mfma_f32_16x16x32_bf16(hf,  biz, accz[c], 0, 0, 0);
                accz[c]  = __builtin_amdgcn_mfma_f32_16x16x32_bf16(hpf, bhz, accz[c], 0, 0, 0);
                accin[c] = __builtin_amdgcn_mfma_f32_16x16x32_bf16(hf,  bin2, accin[c], 0, 0, 0);
                acchn[c] = __builtin_amdgcn_mfma_f32_16x16x32_bf16(hpf, bhn2, acchn[c], 0, 0, 0);
            }
        }
        float p0[4] = {0,0,0,0}, p1[4] = {0,0,0,0}, p2[4] = {0,0,0,0};
        #pragma unroll
        for (int c = 0; c < 4; c++) {
            #pragma unroll
            for (int reg = 0; reg < 4; reg++) {
                float rr = sigm(accr[c][reg]);
                float zz = sigm(accz[c][reg]);
                float ng = tanhf(accin[c][reg] + rr * acchn[c][reg]);
                long n = nb + q * 4 + reg;
                long j = c * 16 + cl;
                float hp = ldv(h_prev, n * 64 + j, isf);
                float hx = (1.f - zz) * ng + zz * hp;
                stv(out, n * 64 + j, hx, isf);
                p0[reg] += hx * wo0[c];
                p1[reg] += hx * wo1[c];
                p2[reg] += hx * wo2[c];
            }
        }
        #pragma unroll
        for (int reg = 0; reg < 4; reg++) {
            #pragma unroll
            for (int off2 = 1; off2 < 16; off2 <<= 1) {
                p0[reg] += __shfl_xor(p0[reg], off2);
                p1[reg] += __shfl_xor(p1[reg], off2);
                p2[reg] += __shfl_xor(p2[reg], off2);
            }
        }
        if (cl == 0) {
            #pragma unroll
            for (int reg = 0; reg < 4; reg++) {
                long n = nb + q * 4 + reg;
                long pb = (long)NN * 64 + n * 3;
                stv(out, pb + 0, p0[reg] + bo0, isf);
                stv(out, pb + 1, p1[reg] + bo1, isf);
                stv(out, pb + 2, p2[reg] + bo2, isf);
            }
        }
    }
}

extern "C" void kernel_launch(void* const* d_in, const int* in_sizes, int n_in,
                              void* d_out, int out_size, void* d_ws, size_t ws_size,
                              hipStream_t stream) {
    const void* x      = d_in[0];
    const void* h_prev = d_in[1];
    const int* en      = (const int*)d_in[2];
    const int* eh      = (const int*)d_in[3];
    const int* ea      = (const int*)d_in[4];
    const void* W_conv = d_in[5];
    const void* b_conv = d_in[6];
    const void* W_mix  = d_in[7];
    const void* b_mix  = d_in[8];
    const void* W_ih   = d_in[9];
    const void* W_hh   = d_in[10];
    const void* b_ih   = d_in[11];
    const void* b_hh   = d_in[12];
    const void* W_out  = d_in[13];
    const void* b_out  = d_in[14];
    void* out          = d_out;

    float* ws    = (float*)d_ws;
    u32* bkt1    = (u32*)(ws + OFF_BKT1);
    u32* bkt2    = (u32*)(ws + OFF_BKT2);
    u32* exb     = (u32*)(ws + OFF_EXB);
    int* fscan   = (int*)(ws + OFF_FSC);
    u32* aggb    = (u32*)(ws + OFF_BKT1);   // alias: bkt1 dead after hopA
    float* bcomb = ws + OFF_BCOMB;
    u16* Wihb    = (u16*)(ws + OFF_WIHB);
    u16* Whhb    = (u16*)(ws + OFF_WHHB);
    u16* Wcb     = (u16*)(ws + OFF_WCB);
    u32* flag    = (u32*)(ws + OFF_FLAG);
    int* tot     = (int*)(ws + OFF_TOT);

    detect_kernel<<<1, 256, 0, stream>>>((const u32*)x, flag);
    setup_kernel<<<(XBASE + 255) / 256, 256, 0, stream>>>(
        W_conv, b_conv, W_mix, b_mix, W_ih, W_hh,
        bcomb, Wihb, Whhb, Wcb, flag);
    countC<<<NCB2, 1024, 0, stream>>>(en, eh, ea, fscan);
    scanA2<<<SCB2, 256, 0, stream>>>(fscan, tot);
    scanB2<<<1, 1024, 0, stream>>>(tot);
    scanC2<<<SCB2, 256, 0, stream>>>(fscan, tot);
    placeC<0><<<NCB2, 1024, 0, stream>>>(en, eh, ea, fscan, bkt1);
    placeC<1><<<NCB2, 1024, 0, stream>>>(en, eh, ea, fscan, bkt2);
    hopA<<<NB1, 512, 0, stream>>>(fscan, bkt1, x, exb, flag);
    hopB<<<NB2, 512, 0, stream>>>(fscan, bkt2, exb, aggb);
    epilogue<<<1563, 256, 0, stream>>>(aggb, bcomb, Wihb, Whhb, Wcb,
                                       b_ih, b_hh, h_prev, W_out, b_out, out, flag);
}